// Round 1
// baseline (230.395 us; speedup 1.0000x reference)
//
#include <hip/hip_runtime.h>

#define N_ENT   50000
#define N_ENT_P 50048
#define NDIM    256
#define BATCH   1024
#define MROWS   2048
#define BM      128
#define BN      128
#define BK      64
#define SHIFT   30.0f

typedef __attribute__((ext_vector_type(8))) short short8;
typedef __attribute__((ext_vector_type(4))) float f32x4;

__device__ __forceinline__ unsigned short f2bf(float f) {
  unsigned int u = __float_as_uint(f);
  u += 0x7fffu + ((u >> 16) & 1u);          // RNE
  return (unsigned short)(u >> 16);
}

__device__ __forceinline__ void async16(const void* g, void* lds) {
  __builtin_amdgcn_global_load_lds(
      (const __attribute__((address_space(1))) unsigned int*)g,
      (__attribute__((address_space(3))) unsigned int*)lds,
      16, 0, 0);
}

// ---- K0: ent_w f32 -> bf16 bits, zero-pad rows [50000,50048) ----
__global__ void k_convert(const float* __restrict__ ent_w,
                          unsigned short* __restrict__ Wb) {
  int t = blockIdx.x * 256 + threadIdx.x;     // [0, 50048*64)
  int row = t >> 6, c4 = (t & 63) << 2;
  ushort4 v;
  if (row < N_ENT) {
    float4 f = *(const float4*)(ent_w + row * NDIM + c4);
    v.x = f2bf(f.x); v.y = f2bf(f.y); v.z = f2bf(f.z); v.w = f2bf(f.w);
  } else {
    v.x = v.y = v.z = v.w = 0;
  }
  *(ushort4*)(Wb + row * NDIM + c4) = v;
}

// ---- K1: BN stats (sum, sumsq) over gathered rows, per dim, 3 segs ----
__global__ void k_stats(const int* __restrict__ facts,
                        const float* __restrict__ ent_w,
                        const float* __restrict__ rel_w,
                        float* __restrict__ stats) {
  int seg = blockIdx.y;                        // 0=h, 1=t, 2=r
  int d = threadIdx.x;
  const float* tab = (seg == 2) ? rel_w : ent_w;
  float s = 0.f, s2 = 0.f;
  int r0 = blockIdx.x * 64;
  for (int i = 0; i < 64; ++i) {
    int idx = facts[(r0 + i) * 3 + seg];
    float v = tab[idx * NDIM + d];
    s += v; s2 += v * v;
  }
  atomicAdd(&stats[(seg * 2 + 0) * NDIM + d], s);
  atomicAdd(&stats[(seg * 2 + 1) * NDIM + d], s2);
}

// ---- K2: BN apply + alpha bilinear -> head/tail vec (bf16) + exact label dots ----
__global__ void k_vectors(const int* __restrict__ facts, const int* __restrict__ arch,
                          const float* __restrict__ ent_w, const float* __restrict__ rel_w,
                          const float* __restrict__ bne_g, const float* __restrict__ bne_b,
                          const float* __restrict__ bnr_g, const float* __restrict__ bnr_b,
                          const float* __restrict__ stats,
                          unsigned short* __restrict__ HVb, float* __restrict__ zlab) {
  __shared__ float sh_he[256], sh_te[256], sh_re[256], sh_alpha[64], sh_red[16];
  int b = blockIdx.x, d = threadIdx.x;
  int h = facts[b * 3 + 0], t = facts[b * 3 + 1], r = facts[b * 3 + 2];
  const float inv = 1.0f / (float)BATCH;
  float mh = stats[0 * 256 + d] * inv, vh = stats[1 * 256 + d] * inv - mh * mh;
  float mt = stats[2 * 256 + d] * inv, vt = stats[3 * 256 + d] * inv - mt * mt;
  float mr = stats[4 * 256 + d] * inv, vr = stats[5 * 256 + d] * inv - mr * mr;
  float sch = rsqrtf(vh + 1e-5f) * bne_g[d], shh = bne_b[d] - mh * sch;
  float sct = rsqrtf(vt + 1e-5f) * bne_g[d], sht = bne_b[d] - mt * sct;
  float scr = rsqrtf(vr + 1e-5f) * bnr_g[d], shr = bnr_b[d] - mr * scr;
  sh_he[d] = ent_w[h * NDIM + d] * sch + shh;
  sh_te[d] = ent_w[t * NDIM + d] * sct + sht;
  sh_re[d] = rel_w[r * NDIM + d] * scr + shr;
  if (d < 64) {
    int a = arch[d];
    sh_alpha[d] = (a == 0) ? 0.f : ((a == 1) ? 1.f : -1.f);
  }
  __syncthreads();
  int k = d >> 6, l = d & 63;
  float hv = 0.f, tv = 0.f;
#pragma unroll
  for (int i = 0; i < 4; ++i) {
    float re_i = sh_re[i * 64 + l];
#pragma unroll
    for (int j = 0; j < 4; ++j) {
      hv += sh_alpha[i * 16 + j * 4 + k] * re_i * sh_te[j * 64 + l];
      tv += sh_alpha[i * 16 + k * 4 + j] * re_i * sh_he[j * 64 + l];
    }
  }
  HVb[b * NDIM + d] = f2bf(hv);
  HVb[(BATCH + b) * NDIM + d] = f2bf(tv);
  // exact f32 label logits: head vs ent_w[h], tail vs ent_w[t]
  float ph = hv * ent_w[h * NDIM + d];
  float pt = tv * ent_w[t * NDIM + d];
  for (int m = 1; m < 64; m <<= 1) { ph += __shfl_xor(ph, m); pt += __shfl_xor(pt, m); }
  int wid = d >> 6;
  if ((d & 63) == 0) { sh_red[wid] = ph; sh_red[8 + wid] = pt; }
  __syncthreads();
  if (d == 0) {
    zlab[b] = sh_red[0] + sh_red[1] + sh_red[2] + sh_red[3];
    zlab[BATCH + b] = sh_red[8] + sh_red[9] + sh_red[10] + sh_red[11];
  }
}

// ---- K3: bf16 MFMA GEMM (2048 x 50048 x 256) + fused exp power-sum epilogue ----
__global__ void __launch_bounds__(256, 2)
k_gemm(const unsigned short* __restrict__ HVb, const unsigned short* __restrict__ Wb,
       float* __restrict__ m1, float* __restrict__ m2,
       float* __restrict__ m3, float* __restrict__ m4) {
  __shared__ __align__(16) unsigned short As[BM * BK];   // 16 KB, swizzled granules
  __shared__ __align__(16) unsigned short Bs[BN * BK];   // 16 KB
  const int tid = threadIdx.x;
  const int lane = tid & 63, wid = tid >> 6;
  const int bm = blockIdx.x * BM;
  const int bn = blockIdx.y * BN;
  const int wm = (wid & 1) * 64, wn = (wid >> 1) * 64;
  f32x4 acc[4][4] = {};

  for (int kc = 0; kc < NDIM; kc += BK) {
    __syncthreads();   // protect LDS from previous iteration's reads
#pragma unroll
    for (int c = 0; c < 4; ++c) {
      int G = (wid * 4 + c) * 64 + lane;       // granule id in [0,1024)
      int row = G >> 3, slot = G & 7;
      int kg = slot ^ (row & 7);               // XOR swizzle: logical k-group at this slot
      async16(HVb + (bm + row) * NDIM + kc + kg * 8,
              (char*)As + (wid * 4 + c) * 1024);
      async16(Wb + (bn + row) * NDIM + kc + kg * 8,
              (char*)Bs + (wid * 4 + c) * 1024);
    }
    __syncthreads();   // drains vmcnt before barrier
    const int q = lane >> 4, ln = lane & 15;
#pragma unroll
    for (int kk = 0; kk < BK; kk += 32) {
      short8 a[4], bb[4];
      int kg = (kk >> 3) + q;
#pragma unroll
      for (int mi = 0; mi < 4; ++mi) {
        int row = wm + mi * 16 + ln;
        a[mi] = *(const short8*)((const char*)As + row * 128 + (kg ^ (row & 7)) * 16);
      }
#pragma unroll
      for (int ni = 0; ni < 4; ++ni) {
        int row = wn + ni * 16 + ln;
        bb[ni] = *(const short8*)((const char*)Bs + row * 128 + (kg ^ (row & 7)) * 16);
      }
#pragma unroll
      for (int mi = 0; mi < 4; ++mi)
#pragma unroll
        for (int ni = 0; ni < 4; ++ni)
          acc[mi][ni] = __builtin_amdgcn_mfma_f32_16x16x32_bf16(a[mi], bb[ni], acc[mi][ni], 0, 0, 0);
    }
  }

  // epilogue: per-row power sums of exp(z - SHIFT)
  const int q = lane >> 4, cn = lane & 15;
#pragma unroll
  for (int mi = 0; mi < 4; ++mi) {
#pragma unroll
    for (int reg = 0; reg < 4; ++reg) {
      float s1 = 0.f, s2 = 0.f, s3 = 0.f, s4 = 0.f;
#pragma unroll
      for (int ni = 0; ni < 4; ++ni) {
        int gcol = bn + wn + ni * 16 + cn;
        float z = acc[mi][ni][reg];
        if (gcol < N_ENT) {
          float e1 = __expf(z - SHIFT);
          float e2 = e1 * e1;
          s1 += e1; s2 += e2; s3 += e2 * e1; s4 += e2 * e2;
        }
      }
      for (int m = 1; m < 16; m <<= 1) {
        s1 += __shfl_xor(s1, m); s2 += __shfl_xor(s2, m);
        s3 += __shfl_xor(s3, m); s4 += __shfl_xor(s4, m);
      }
      if (cn == 0) {
        int grow = bm + wm + mi * 16 + q * 4 + reg;
        atomicAdd(&m1[grow], s1);
        atomicAdd(&m2[grow], s2);
        atomicAdd(&m3[grow], s3);
        atomicAdd(&m4[grow], s4);
      }
    }
  }
}

// ---- K4: per-row loss assembly + scalar reduce ----
__global__ void k_finalize(const float* __restrict__ m1, const float* __restrict__ m2,
                           const float* __restrict__ m3, const float* __restrict__ m4,
                           const float* __restrict__ zlab, float* __restrict__ out) {
  __shared__ float red[16];
  int tid = threadIdx.x;  // 1024 threads
  float local = 0.f;
  for (int r = tid; r < MROWS; r += 1024) {
    float M1 = m1[r];
    float lse = SHIFT + logf(M1);
    float zl = zlab[r];
    float lp = fmaxf(zl - lse, -100.f);                 // log p_label (clamped)
    float pl = __expf(zl - lse);
    float l1m = fmaxf(log1pf(-pl), -100.f);             // log(1-p_label) (clamped)
    float iM1 = 1.f / M1;
    float r2 = m2[r] * iM1 * iM1;
    float r3 = m3[r] * iM1 * iM1 * iM1;
    float r4 = m4[r] * iM1 * iM1 * iM1 * iM1;
    // sum_e log1p(-p_e) = -(sum p + sum p^2/2 + sum p^3/3 + sum p^4/4 + ...), sum p == 1
    float series = -(1.f + 0.5f * r2 + (1.f / 3.f) * r3 + 0.25f * r4);
    local += lp - l1m + series;
  }
  for (int m = 1; m < 64; m <<= 1) local += __shfl_xor(local, m);
  if ((tid & 63) == 0) red[tid >> 6] = local;
  __syncthreads();
  if (tid == 0) {
    float s = 0.f;
    for (int i = 0; i < 16; ++i) s += red[i];
    out[0] = -s / ((float)BATCH * (float)N_ENT);
  }
}

extern "C" void kernel_launch(void* const* d_in, const int* in_sizes, int n_in,
                              void* d_out, int out_size, void* d_ws, size_t ws_size,
                              hipStream_t stream) {
  const int* facts = (const int*)d_in[0];
  const int* arch = (const int*)d_in[1];
  const float* ent_w = (const float*)d_in[2];
  const float* rel_w = (const float*)d_in[3];
  const float* bne_g = (const float*)d_in[4];
  const float* bne_b = (const float*)d_in[5];
  const float* bnr_g = (const float*)d_in[6];
  const float* bnr_b = (const float*)d_in[7];
  char* ws = (char*)d_ws;
  // layout: [stats 6144B][m1 8192][m2 8192][m3 8192][m4 8192][zlab 8192][HVb 1MB][Wb 25.6MB]
  float* stats = (float*)ws;
  float* m1 = (float*)(ws + 6144);
  float* m2 = (float*)(ws + 14336);
  float* m3 = (float*)(ws + 22528);
  float* m4 = (float*)(ws + 30720);
  float* zlab = (float*)(ws + 38912);
  unsigned short* HVb = (unsigned short*)(ws + 47104);
  unsigned short* Wb = (unsigned short*)(ws + 47104 + 1048576);

  hipMemsetAsync(ws, 0, 38912, stream);  // stats + m1..m4
  k_convert<<<dim3((N_ENT_P * 64) / 256), dim3(256), 0, stream>>>(ent_w, Wb);
  k_stats<<<dim3(16, 3), dim3(256), 0, stream>>>(facts, ent_w, rel_w, stats);
  k_vectors<<<dim3(BATCH), dim3(256), 0, stream>>>(facts, arch, ent_w, rel_w,
                                                   bne_g, bne_b, bnr_g, bnr_b,
                                                   stats, HVb, zlab);
  k_gemm<<<dim3(16, 391), dim3(256), 0, stream>>>(HVb, Wb, m1, m2, m3, m4);
  k_finalize<<<dim3(1), dim3(1024), 0, stream>>>(m1, m2, m3, m4, zlab, (float*)d_out);
}

// Round 2
// 174.876 us; speedup vs baseline: 1.3175x; 1.3175x over previous
//
#include <hip/hip_runtime.h>

#define N_ENT   50000
#define N_ENT_P 50048
#define NDIM    256
#define BATCH   1024
#define MROWS   2048
#define BM      128
#define BN      128
#define BK      64
#define NTILES  391
#define NSTRIP  32
#define SHIFT   30.0f

typedef __attribute__((ext_vector_type(8))) short short8;
typedef __attribute__((ext_vector_type(4))) float f32x4;

__device__ __forceinline__ unsigned short f2bf(float f) {
  unsigned int u = __float_as_uint(f);
  u += 0x7fffu + ((u >> 16) & 1u);          // RNE
  return (unsigned short)(u >> 16);
}

__device__ __forceinline__ void async16(const void* g, void* lds) {
  __builtin_amdgcn_global_load_lds(
      (const __attribute__((address_space(1))) unsigned int*)g,
      (__attribute__((address_space(3))) unsigned int*)lds,
      16, 0, 0);
}

// ---- K0: ent_w f32 -> bf16 bits, zero-pad rows [50000,50048) ----
__global__ void k_convert(const float* __restrict__ ent_w,
                          unsigned short* __restrict__ Wb) {
  int t = blockIdx.x * 256 + threadIdx.x;     // [0, 50048*64)
  int row = t >> 6, c4 = (t & 63) << 2;
  ushort4 v;
  if (row < N_ENT) {
    float4 f = *(const float4*)(ent_w + row * NDIM + c4);
    v.x = f2bf(f.x); v.y = f2bf(f.y); v.z = f2bf(f.z); v.w = f2bf(f.w);
  } else {
    v.x = v.y = v.z = v.w = 0;
  }
  *(ushort4*)(Wb + row * NDIM + c4) = v;
}

// ---- K1: BN stats (sum, sumsq); 16 rows/block, indices prefetched ----
__global__ void k_stats(const int* __restrict__ facts,
                        const float* __restrict__ ent_w,
                        const float* __restrict__ rel_w,
                        float* __restrict__ stats) {
  int seg = blockIdx.y;                        // 0=h, 1=t, 2=r
  int d = threadIdx.x;
  const float* tab = (seg == 2) ? rel_w : ent_w;
  int r0 = blockIdx.x * 16;
  int idxs[16];
#pragma unroll
  for (int i = 0; i < 16; ++i) idxs[i] = facts[(r0 + i) * 3 + seg];
  float s = 0.f, s2 = 0.f;
#pragma unroll
  for (int i = 0; i < 16; ++i) {
    float v = tab[idxs[i] * NDIM + d];
    s += v; s2 += v * v;
  }
  atomicAdd(&stats[(seg * 2 + 0) * NDIM + d], s);
  atomicAdd(&stats[(seg * 2 + 1) * NDIM + d], s2);
}

// ---- K2: BN apply + alpha bilinear -> head/tail vec (bf16) + exact label dots ----
__global__ void k_vectors(const int* __restrict__ facts, const int* __restrict__ arch,
                          const float* __restrict__ ent_w, const float* __restrict__ rel_w,
                          const float* __restrict__ bne_g, const float* __restrict__ bne_b,
                          const float* __restrict__ bnr_g, const float* __restrict__ bnr_b,
                          const float* __restrict__ stats,
                          unsigned short* __restrict__ HVb, float* __restrict__ zlab) {
  __shared__ float sh_he[256], sh_te[256], sh_re[256], sh_alpha[64], sh_red[16];
  int b = blockIdx.x, d = threadIdx.x;
  int h = facts[b * 3 + 0], t = facts[b * 3 + 1], r = facts[b * 3 + 2];
  const float inv = 1.0f / (float)BATCH;
  float mh = stats[0 * 256 + d] * inv, vh = stats[1 * 256 + d] * inv - mh * mh;
  float mt = stats[2 * 256 + d] * inv, vt = stats[3 * 256 + d] * inv - mt * mt;
  float mr = stats[4 * 256 + d] * inv, vr = stats[5 * 256 + d] * inv - mr * mr;
  float sch = rsqrtf(vh + 1e-5f) * bne_g[d], shh = bne_b[d] - mh * sch;
  float sct = rsqrtf(vt + 1e-5f) * bne_g[d], sht = bne_b[d] - mt * sct;
  float scr = rsqrtf(vr + 1e-5f) * bnr_g[d], shr = bnr_b[d] - mr * scr;
  sh_he[d] = ent_w[h * NDIM + d] * sch + shh;
  sh_te[d] = ent_w[t * NDIM + d] * sct + sht;
  sh_re[d] = rel_w[r * NDIM + d] * scr + shr;
  if (d < 64) {
    int a = arch[d];
    sh_alpha[d] = (a == 0) ? 0.f : ((a == 1) ? 1.f : -1.f);
  }
  __syncthreads();
  int k = d >> 6, l = d & 63;
  float hv = 0.f, tv = 0.f;
#pragma unroll
  for (int i = 0; i < 4; ++i) {
    float re_i = sh_re[i * 64 + l];
#pragma unroll
    for (int j = 0; j < 4; ++j) {
      hv += sh_alpha[i * 16 + j * 4 + k] * re_i * sh_te[j * 64 + l];
      tv += sh_alpha[i * 16 + k * 4 + j] * re_i * sh_he[j * 64 + l];
    }
  }
  HVb[b * NDIM + d] = f2bf(hv);
  HVb[(BATCH + b) * NDIM + d] = f2bf(tv);
  float ph = hv * ent_w[h * NDIM + d];
  float pt = tv * ent_w[t * NDIM + d];
  for (int m = 1; m < 64; m <<= 1) { ph += __shfl_xor(ph, m); pt += __shfl_xor(pt, m); }
  int wid = d >> 6;
  if ((d & 63) == 0) { sh_red[wid] = ph; sh_red[8 + wid] = pt; }
  __syncthreads();
  if (d == 0) {
    zlab[b] = sh_red[0] + sh_red[1] + sh_red[2] + sh_red[3];
    zlab[BATCH + b] = sh_red[8] + sh_red[9] + sh_red[10] + sh_red[11];
  }
}

// ---- K3: bf16 MFMA GEMM (2048 x 50048 x 256), N-strip per block,
//          register power-sum accumulation, one atomic round per block ----
__global__ void __launch_bounds__(256, 2)
k_gemm(const unsigned short* __restrict__ HVb, const unsigned short* __restrict__ Wb,
       float* __restrict__ m1, float* __restrict__ m2) {
  __shared__ __align__(16) unsigned short As[BM * BK];   // 16 KB, swizzled granules
  __shared__ __align__(16) unsigned short Bs[BN * BK];   // 16 KB
  const int tid = threadIdx.x;
  const int lane = tid & 63, wid = tid >> 6;
  // XCD swizzle: all 16 m-tiles of a strip land on one XCD (L%8 round-robin).
  const int L = blockIdx.x;                   // [0, 512)
  const int xcd = L & 7, r = L >> 3;          // r in [0,64)
  const int strip = xcd * 4 + (r >> 4);       // [0,32)
  const int bm = (r & 15) * BM;
  const int wm = (wid & 1) * 64, wn = (wid >> 1) * 64;
  const int q = lane >> 4, ln = lane & 15;

  float ps1[4][4] = {}, ps2[4][4] = {};

  for (int nt = strip; nt < NTILES; nt += NSTRIP) {
    const int bn = nt * BN;
    f32x4 acc[4][4] = {};
    for (int kc = 0; kc < NDIM; kc += BK) {
      __syncthreads();   // protect LDS from previous iteration's reads
#pragma unroll
      for (int c = 0; c < 4; ++c) {
        int G = (wid * 4 + c) * 64 + lane;     // granule id in [0,1024)
        int row = G >> 3, slot = G & 7;
        int kg = slot ^ (row & 7);             // XOR swizzle
        async16(HVb + (bm + row) * NDIM + kc + kg * 8,
                (char*)As + (wid * 4 + c) * 1024);
        async16(Wb + (bn + row) * NDIM + kc + kg * 8,
                (char*)Bs + (wid * 4 + c) * 1024);
      }
      __syncthreads();   // drains vmcnt before barrier
#pragma unroll
      for (int kk = 0; kk < BK; kk += 32) {
        short8 a[4], bb[4];
        int kg = (kk >> 3) + q;
#pragma unroll
        for (int mi = 0; mi < 4; ++mi) {
          int row = wm + mi * 16 + ln;
          a[mi] = *(const short8*)((const char*)As + row * 128 + ((kg ^ (row & 7)) << 4));
        }
#pragma unroll
        for (int ni = 0; ni < 4; ++ni) {
          int row = wn + ni * 16 + ln;
          bb[ni] = *(const short8*)((const char*)Bs + row * 128 + ((kg ^ (row & 7)) << 4));
        }
#pragma unroll
        for (int mi = 0; mi < 4; ++mi)
#pragma unroll
          for (int ni = 0; ni < 4; ++ni)
            acc[mi][ni] = __builtin_amdgcn_mfma_f32_16x16x32_bf16(a[mi], bb[ni], acc[mi][ni], 0, 0, 0);
      }
    }
    // consume acc into register power sums (pad cols contribute e^-30 ~ 0)
#pragma unroll
    for (int mi = 0; mi < 4; ++mi)
#pragma unroll
      for (int reg = 0; reg < 4; ++reg) {
        float s1 = 0.f, s2 = 0.f;
#pragma unroll
        for (int ni = 0; ni < 4; ++ni) {
          float e1 = __expf(acc[mi][ni][reg] - SHIFT);
          s1 += e1; s2 += e1 * e1;
        }
        ps1[mi][reg] += s1;
        ps2[mi][reg] += s2;
      }
  }

  // one reduce + atomic round per block
#pragma unroll
  for (int mi = 0; mi < 4; ++mi)
#pragma unroll
    for (int reg = 0; reg < 4; ++reg) {
      float s1 = ps1[mi][reg], s2 = ps2[mi][reg];
      for (int m = 1; m < 16; m <<= 1) { s1 += __shfl_xor(s1, m); s2 += __shfl_xor(s2, m); }
      if (ln == 0) {
        int grow = bm + wm + mi * 16 + q * 4 + reg;
        atomicAdd(&m1[grow], s1);
        atomicAdd(&m2[grow], s2);
      }
    }
}

// ---- K4: per-row loss assembly + scalar reduce ----
__global__ void k_finalize(const float* __restrict__ m1, const float* __restrict__ m2,
                           const float* __restrict__ zlab, float* __restrict__ out) {
  __shared__ float red[16];
  int tid = threadIdx.x;  // 1024 threads
  float local = 0.f;
  for (int r = tid; r < MROWS; r += 1024) {
    float M1 = m1[r];
    float lse = SHIFT + logf(M1);
    float zl = zlab[r];
    float lp = fmaxf(zl - lse, -100.f);                 // log p_label
    float pl = __expf(zl - lse);
    float l1m = fmaxf(log1pf(-pl), -100.f);             // log(1-p_label)
    float iM1 = 1.f / M1;
    float r2 = m2[r] * iM1 * iM1;
    // sum_e log1p(-p_e) = -(1 + sum p^2/2 + O(p^3)); sum p == 1 exactly
    float series = -(1.f + 0.5f * r2);
    local += lp - l1m + series;
  }
  for (int m = 1; m < 64; m <<= 1) local += __shfl_xor(local, m);
  if ((tid & 63) == 0) red[tid >> 6] = local;
  __syncthreads();
  if (tid == 0) {
    float s = 0.f;
    for (int i = 0; i < 16; ++i) s += red[i];
    out[0] = -s / ((float)BATCH * (float)N_ENT);
  }
}

extern "C" void kernel_launch(void* const* d_in, const int* in_sizes, int n_in,
                              void* d_out, int out_size, void* d_ws, size_t ws_size,
                              hipStream_t stream) {
  const int* facts = (const int*)d_in[0];
  const int* arch = (const int*)d_in[1];
  const float* ent_w = (const float*)d_in[2];
  const float* rel_w = (const float*)d_in[3];
  const float* bne_g = (const float*)d_in[4];
  const float* bne_b = (const float*)d_in[5];
  const float* bnr_g = (const float*)d_in[6];
  const float* bnr_b = (const float*)d_in[7];
  char* ws = (char*)d_ws;
  // layout: [stats 6144][m1 8192][m2 8192][zlab 8192][HVb 1MB][Wb 25.6MB]
  float* stats = (float*)ws;
  float* m1 = (float*)(ws + 6144);
  float* m2 = (float*)(ws + 14336);
  float* zlab = (float*)(ws + 22528);
  unsigned short* HVb = (unsigned short*)(ws + 30720);
  unsigned short* Wb = (unsigned short*)(ws + 30720 + 1048576);

  hipMemsetAsync(ws, 0, 22528, stream);  // stats + m1 + m2
  k_convert<<<dim3((N_ENT_P * 64) / 256), dim3(256), 0, stream>>>(ent_w, Wb);
  k_stats<<<dim3(64, 3), dim3(256), 0, stream>>>(facts, ent_w, rel_w, stats);
  k_vectors<<<dim3(BATCH), dim3(256), 0, stream>>>(facts, arch, ent_w, rel_w,
                                                   bne_g, bne_b, bnr_g, bnr_b,
                                                   stats, HVb, zlab);
  k_gemm<<<dim3(512), dim3(256), 0, stream>>>(HVb, Wb, m1, m2);
  k_finalize<<<dim3(1), dim3(1024), 0, stream>>>(m1, m2, zlab, (float*)d_out);
}